// Round 16
// baseline (388.791 us; speedup 1.0000x reference)
//
#include <hip/hip_runtime.h>
#include <hip/hip_bf16.h>

// Problem constants
#define BB 2
#define LL 1024
#define DD 1024
#define DI 2048
#define SS 16
#define KK 4
#define RR 64
#define MROWS (BB*LL)   // 2048
#define NCT 32          // t-chunks for scan
#define CTL 32          // steps per chunk (LL / NCT)

typedef __attribute__((ext_vector_type(8))) short short8;     // 8 bf16 = 4 VGPR
typedef __attribute__((ext_vector_type(4))) float floatx4;    // MFMA C/D

// RNE fp32 -> bf16 bits
__device__ __forceinline__ unsigned short f2bf(float v) {
    unsigned int u = __float_as_uint(v);
    return (unsigned short)((u + 0x7FFFu + ((u >> 16) & 1u)) >> 16);
}
__device__ __forceinline__ float bf2f(unsigned short h) {
    return __uint_as_float(((unsigned int)h) << 16);
}
__device__ __forceinline__ void split1(float v, unsigned short& a,
                                       unsigned short& b, unsigned short& c) {
    a = f2bf(v);
    float r = v - bf2f(a);
    b = f2bf(r);
    float r2 = r - bf2f(b);
    c = f2bf(r2);
}

__device__ __forceinline__ void split3_body(const float4* __restrict__ src,
                                            ushort4* __restrict__ d1,
                                            ushort4* __restrict__ d2,
                                            ushort4* __restrict__ d3,
                                            int i0, int stride, int n4) {
    for (int i = i0; i < n4; i += stride) {
        const float4 v = src[i];
        ushort4 o1, o2, o3;
        split1(v.x, o1.x, o2.x, o3.x);
        split1(v.y, o1.y, o2.y, o3.y);
        split1(v.z, o1.z, o2.z, o3.z);
        split1(v.w, o1.w, o2.w, o3.w);
        d1[i] = o1; d2[i] = o2; d3[i] = o3;
    }
}

__global__ __launch_bounds__(256) void split3(const float4* __restrict__ src,
                                              ushort4* __restrict__ d1,
                                              ushort4* __restrict__ d2,
                                              ushort4* __restrict__ d3, int n4) {
    split3_body(src, d1, d2, d3, blockIdx.x * 256 + threadIdx.x, gridDim.x * 256, n4);
}

__global__ __launch_bounds__(256) void split3_2(
    const float4* __restrict__ s0, ushort4* __restrict__ a1,
    ushort4* __restrict__ a2, ushort4* __restrict__ a3, int n0,
    const float4* __restrict__ s1, ushort4* __restrict__ b1,
    ushort4* __restrict__ b2, ushort4* __restrict__ b3, int n1, int nb0) {
    if ((int)blockIdx.x < nb0) {
        split3_body(s0, a1, a2, a3, blockIdx.x * 256 + threadIdx.x, nb0 * 256, n0);
    } else {
        const int nb1 = gridDim.x - nb0;
        split3_body(s1, b1, b2, b3, (blockIdx.x - nb0) * 256 + threadIdx.x, nb1 * 256, n1);
    }
}

// ---------------------------------------------------------------------------
// Split-bf16 MFMA GEMM (round-13: k-quad-major LDS, reg prefetch). UNCHANGED.
// ---------------------------------------------------------------------------
__global__ __launch_bounds__(256, 3) void gemm_mfma_split(
    const unsigned short* __restrict__ A1, const unsigned short* __restrict__ A2,
    const unsigned short* __restrict__ A3,
    const unsigned short* __restrict__ B1, const unsigned short* __restrict__ B2,
    const unsigned short* __restrict__ B3,
    float* __restrict__ C0, float* __restrict__ Cpart,
    int M, int N, int Kstride, int Klen) {
    __shared__ unsigned short As[3][4][128][8];
    __shared__ unsigned short Bs[3][4][128][8];
    const int tid = threadIdx.x;
    const int bm = blockIdx.y * 128;
    const int bn = blockIdx.x * 128;
    const int Koff = blockIdx.z * Klen;
    float* __restrict__ C = (blockIdx.z == 0)
        ? C0 : (Cpart + (size_t)(blockIdx.z - 1) * M * N);

    const int lane = tid & 63;
    const int wv = tid >> 6;
    const int lm = lane & 15;
    const int kq = lane >> 4;
    const int wm = (wv >> 1) * 64;
    const int wn = (wv & 1) * 64;

    floatx4 acc[4][4];
    const floatx4 zf = {0.f, 0.f, 0.f, 0.f};
#pragma unroll
    for (int i = 0; i < 4; ++i)
#pragma unroll
        for (int j = 0; j < 4; ++j) acc[i][j] = zf;

    const int r0 = tid >> 1;
    const int cc = tid & 1;
    const int cc0 = cc * 16;
    const int cc1 = cc0 + 8;
    const int q0 = cc * 2, q1 = cc * 2 + 1;

    const unsigned short* __restrict__ Ar1 = A1 + (size_t)(bm + r0) * Kstride;
    const unsigned short* __restrict__ Ar2 = A2 + (size_t)(bm + r0) * Kstride;
    const unsigned short* __restrict__ Ar3 = A3 + (size_t)(bm + r0) * Kstride;
    const unsigned short* __restrict__ Br1 = B1 + (size_t)(bn + r0) * Kstride;
    const unsigned short* __restrict__ Br2 = B2 + (size_t)(bn + r0) * Kstride;
    const unsigned short* __restrict__ Br3 = B3 + (size_t)(bn + r0) * Kstride;

    short8 pA[3][2], pB[3][2];
#define LOADK(kt)                                                     \
    {                                                                 \
        pA[0][0] = *(const short8*)&Ar1[(kt) + cc0];                  \
        pA[0][1] = *(const short8*)&Ar1[(kt) + cc1];                  \
        pA[1][0] = *(const short8*)&Ar2[(kt) + cc0];                  \
        pA[1][1] = *(const short8*)&Ar2[(kt) + cc1];                  \
        pA[2][0] = *(const short8*)&Ar3[(kt) + cc0];                  \
        pA[2][1] = *(const short8*)&Ar3[(kt) + cc1];                  \
        pB[0][0] = *(const short8*)&Br1[(kt) + cc0];                  \
        pB[0][1] = *(const short8*)&Br1[(kt) + cc1];                  \
        pB[1][0] = *(const short8*)&Br2[(kt) + cc0];                  \
        pB[1][1] = *(const short8*)&Br2[(kt) + cc1];                  \
        pB[2][0] = *(const short8*)&Br3[(kt) + cc0];                  \
        pB[2][1] = *(const short8*)&Br3[(kt) + cc1];                  \
    }

#define PROD(p, bfq)                                                                     \
        _Pragma("unroll")                                                                \
        for (int i = 0; i < 4; ++i)                                                      \
            _Pragma("unroll")                                                            \
            for (int j = 0; j < 4; ++j)                                                  \
                acc[i][j] = __builtin_amdgcn_mfma_f32_16x16x32_bf16(af[p][i], bfq[j],    \
                                                                    acc[i][j], 0, 0, 0);

    LOADK(Koff)
    for (int kt = Koff; kt < Koff + Klen; kt += 32) {
#pragma unroll
        for (int p = 0; p < 3; ++p) {
            *(short8*)&As[p][q0][r0][0] = pA[p][0];
            *(short8*)&As[p][q1][r0][0] = pA[p][1];
            *(short8*)&Bs[p][q0][r0][0] = pB[p][0];
            *(short8*)&Bs[p][q1][r0][0] = pB[p][1];
        }
        __syncthreads();

        const int ktn = (kt + 32 < Koff + Klen) ? (kt + 32) : Koff;
        LOADK(ktn)

        short8 af[3][4];
#pragma unroll
        for (int p = 0; p < 3; ++p)
#pragma unroll
            for (int i = 0; i < 4; ++i)
                af[p][i] = *(const short8*)&As[p][kq][wm + i * 16 + lm][0];

        {
            short8 bfq[4];
#pragma unroll
            for (int j = 0; j < 4; ++j) bfq[j] = *(const short8*)&Bs[0][kq][wn + j * 16 + lm][0];
            PROD(0, bfq)
            PROD(1, bfq)
            PROD(2, bfq)
        }
        {
            short8 bfq[4];
#pragma unroll
            for (int j = 0; j < 4; ++j) bfq[j] = *(const short8*)&Bs[1][kq][wn + j * 16 + lm][0];
            PROD(0, bfq)
            PROD(1, bfq)
        }
        {
            short8 bfq[4];
#pragma unroll
            for (int j = 0; j < 4; ++j) bfq[j] = *(const short8*)&Bs[2][kq][wn + j * 16 + lm][0];
            PROD(0, bfq)
        }
        __syncthreads();
    }
#undef PROD
#undef LOADK

#pragma unroll
    for (int i = 0; i < 4; ++i) {
        const int mrow = bm + wm + i * 16 + kq * 4;
#pragma unroll
        for (int j = 0; j < 4; ++j) {
            const int col = bn + wn + j * 16 + lm;
#pragma unroll
            for (int r = 0; r < 4; ++r)
                C[(size_t)(mrow + r) * N + col] = acc[i][j][r];
        }
    }
}

// ---------------------------------------------------------------------------
__global__ __launch_bounds__(256) void reduce_add3(float4* __restrict__ dst,
                                                   const float4* __restrict__ src,
                                                   int n4) {
    for (int i = blockIdx.x * 256 + threadIdx.x; i < n4; i += gridDim.x * 256) {
        float4 a = dst[i];
        const float4 p0 = src[i];
        const float4 p1 = src[i + (size_t)n4];
        const float4 p2 = src[i + (size_t)2 * n4];
        a.x += p0.x + p1.x + p2.x;
        a.y += p0.y + p1.y + p2.y;
        a.z += p0.z + p1.z + p2.z;
        a.w += p0.w + p1.w + p2.w;
        dst[i] = a;
    }
}

// ---------------------------------------------------------------------------
// Depthwise causal conv (K=4) + bias + silu, 8 t-steps/thread (unchanged)
// ---------------------------------------------------------------------------
__global__ __launch_bounds__(256) void conv_silu_rm8(const float* __restrict__ xz,
                                                     const float* __restrict__ Wc,
                                                     const float* __restrict__ bc,
                                                     float* __restrict__ u,
                                                     float* __restrict__ zs) {
    const int c = blockIdx.x * 256 + threadIdx.x;
    const int t0 = blockIdx.y * 8;
    const int b = blockIdx.z;
    const float* xcol = xz + (size_t)b * LL * (2 * DI) + c;
    const float w0 = Wc[c * 4 + 0], w1 = Wc[c * 4 + 1];
    const float w2 = Wc[c * 4 + 2], w3 = Wc[c * 4 + 3];
    const float bcv = bc[c];

    float x[11];
#pragma unroll
    for (int i = 0; i < 11; ++i) {
        const int t = t0 - 3 + i;
        x[i] = (t >= 0) ? xcol[(size_t)t * (2 * DI)] : 0.f;
    }
#pragma unroll
    for (int j = 0; j < 8; ++j) {
        const float acc = bcv + x[j] * w0 + x[j + 1] * w1 + x[j + 2] * w2 + x[j + 3] * w3;
        const float zv = xcol[(size_t)(t0 + j) * (2 * DI) + DI];
        const size_t o = ((size_t)b * LL + t0 + j) * DI + c;
        u[o]  = acc / (1.f + __expf(-acc));
        zs[o] = zv / (1.f + __expf(-zv));
    }
}

// ---------------------------------------------------------------------------
// proj split-K=4 (unchanged): Pp[kz][m][96]
// ---------------------------------------------------------------------------
__global__ __launch_bounds__(256) void proj_gemm_sk(const float* __restrict__ U,
                                                    const float* __restrict__ Wx,
                                                    float* __restrict__ Pp) {
    const int BKp = 64;
    __shared__ float Us[16][68];
    __shared__ float Ws[96][68];
    const int tid = threadIdx.x;
    const int m0 = blockIdx.x * 16;
    const int Koff = blockIdx.y * (DI / 4);
    float* __restrict__ P = Pp + (size_t)blockIdx.y * MROWS * 96;
    const int tx = tid & 31;
    const int ty = tid >> 5;
    float acc[2][3] = {{0.f, 0.f, 0.f}, {0.f, 0.f, 0.f}};

    for (int kt = Koff; kt < Koff + DI / 4; kt += BKp) {
        {
            const int r = tid >> 4;
            const int c4 = (tid & 15) << 2;
            *(float4*)&Us[r][c4] = *(const float4*)&U[(size_t)(m0 + r) * DI + kt + c4];
        }
#pragma unroll
        for (int i = 0; i < 6; ++i) {
            const int idx = tid + i * 256;
            const int r = idx >> 4;
            const int c4 = (idx & 15) << 2;
            *(float4*)&Ws[r][c4] = *(const float4*)&Wx[(size_t)r * DI + kt + c4];
        }
        __syncthreads();
#pragma unroll
        for (int k4 = 0; k4 < BKp; k4 += 4) {
            const float4 u0 = *(const float4*)&Us[ty * 2][k4];
            const float4 u1 = *(const float4*)&Us[ty * 2 + 1][k4];
#pragma unroll
            for (int j = 0; j < 3; ++j) {
                const float4 w = *(const float4*)&Ws[tx + 32 * j][k4];
                acc[0][j] += u0.x * w.x + u0.y * w.y + u0.z * w.z + u0.w * w.w;
                acc[1][j] += u1.x * w.x + u1.y * w.y + u1.z * w.z + u1.w * w.w;
            }
        }
        __syncthreads();
    }
#pragma unroll
    for (int i = 0; i < 2; ++i)
#pragma unroll
        for (int j = 0; j < 3; ++j)
            P[(size_t)(m0 + ty * 2 + i) * 96 + tx + 32 * j] = acc[i][j];
}

// ---------------------------------------------------------------------------
// dt[m][c] = softplus(sum_kz Pp[kz][m][:64] @ W_dt^T + b_dt)
// (proj_reduce fused into the LDS staging; same a+b+c+d order)
// ---------------------------------------------------------------------------
__global__ __launch_bounds__(256) void dt_gemm(const float* __restrict__ Pp,
                                               const float* __restrict__ Wdt,
                                               const float* __restrict__ bdt,
                                               float* __restrict__ dtb) {
    __shared__ float ps[16][68];
    const int tid = threadIdx.x;
    const int c = blockIdx.x * 256 + tid;
    const int m0 = blockIdx.y * 16;
    {
        const int r = tid >> 4;
        const int c4 = (tid & 15) << 2;
        float4 s = make_float4(0.f, 0.f, 0.f, 0.f);
#pragma unroll
        for (int kz = 0; kz < 4; ++kz) {
            const float4 v = *(const float4*)&Pp[(size_t)kz * MROWS * 96
                                                 + (size_t)(m0 + r) * 96 + c4];
            s.x += v.x; s.y += v.y; s.z += v.z; s.w += v.w;
        }
        *(float4*)&ps[r][c4] = s;
    }
    float w[64];
#pragma unroll
    for (int r4 = 0; r4 < 64; r4 += 4) {
        float4 v = *(const float4*)&Wdt[(size_t)c * 64 + r4];
        w[r4] = v.x; w[r4 + 1] = v.y; w[r4 + 2] = v.z; w[r4 + 3] = v.w;
    }
    const float bd = bdt[c];
    __syncthreads();
#pragma unroll 4
    for (int m = 0; m < 16; ++m) {
        float acc = bd;
#pragma unroll
        for (int r4 = 0; r4 < 64; r4 += 4) {
            float4 p = *(const float4*)&ps[m][r4];
            acc += p.x * w[r4] + p.y * w[r4 + 1] + p.z * w[r4 + 2] + p.w * w[r4 + 3];
        }
        const float sp = (acc > 20.f) ? acc : __logf(1.f + __expf(acc));
        dtb[(size_t)(m0 + m) * DI + c] = sp;
    }
}

// ---------------------------------------------------------------------------
// tscan1 with LDS B-slab (2 KB): sums proj partials during preload.
// ---------------------------------------------------------------------------
__global__ __launch_bounds__(256) void tscan1(const float* __restrict__ dtb,
                                              const float* __restrict__ u,
                                              const float* __restrict__ Pp,
                                              const float* __restrict__ A_log,
                                              float* __restrict__ hend,
                                              float* __restrict__ sumdt) {
    __shared__ float Bsl[CTL][16];
    const int c = blockIdx.x * 256 + threadIdx.x;
    const int ch = blockIdx.y;
    const int b = blockIdx.z;
    const size_t m0 = (size_t)b * LL + (size_t)ch * CTL;

    if (threadIdx.x < 128) {
        const int row = threadIdx.x >> 2;
        const int c4 = (threadIdx.x & 3) * 4;
        float4 s = make_float4(0.f, 0.f, 0.f, 0.f);
#pragma unroll
        for (int kz = 0; kz < 4; ++kz) {
            const float4 v = *(const float4*)&Pp[(size_t)kz * MROWS * 96
                                                 + (m0 + row) * 96 + 64 + c4];
            s.x += v.x; s.y += v.y; s.z += v.z; s.w += v.w;
        }
        *(float4*)&Bsl[row][c4] = s;
    }

    float A[16];
#pragma unroll
    for (int s4 = 0; s4 < 16; s4 += 4) {
        float4 v = *(const float4*)&A_log[c * 16 + s4];
        A[s4] = -__expf(v.x); A[s4 + 1] = -__expf(v.y);
        A[s4 + 2] = -__expf(v.z); A[s4 + 3] = -__expf(v.w);
    }
    float h[16];
#pragma unroll
    for (int s = 0; s < 16; ++s) h[s] = 0.f;
    float sd = 0.f;
    __syncthreads();

#pragma unroll 2
    for (int t = 0; t < CTL; ++t) {
        const size_t m = m0 + t;
        const float dt = dtb[m * DI + c];
        const float uv = u[m * DI + c];
        const float dtu = dt * uv;
        sd += dt;
        float bcv[16];
#pragma unroll
        for (int s4 = 0; s4 < 16; s4 += 4) {
            const float4 v = *(const float4*)&Bsl[t][s4];
            bcv[s4] = v.x; bcv[s4 + 1] = v.y; bcv[s4 + 2] = v.z; bcv[s4 + 3] = v.w;
        }
#pragma unroll
        for (int s = 0; s < 16; ++s) {
            const float ab = __expf(dt * A[s]);
            h[s] = ab * h[s] + bcv[s] * dtu;
        }
    }
    const size_t o = (((size_t)b * NCT + ch) * DI + c) * 16;
#pragma unroll
    for (int s4 = 0; s4 < 16; s4 += 4)
        *(float4*)&hend[o + s4] = make_float4(h[s4], h[s4 + 1], h[s4 + 2], h[s4 + 3]);
    sumdt[((size_t)b * NCT + ch) * DI + c] = sd;
}

// ---------------------------------------------------------------------------
__global__ __launch_bounds__(256) void tscan2(float* __restrict__ hend,
                                              const float* __restrict__ sumdt,
                                              const float* __restrict__ A_log) {
    const int id = blockIdx.x * 256 + threadIdx.x;
    const int s = id & 15;
    const int c = (id >> 4) & (DI - 1);
    const int b = id >> 15;
    const float Aval = -__expf(A_log[c * 16 + s]);
    float hs = 0.f;
#pragma unroll
    for (int g = 0; g < 4; ++g) {
        float he[8], sd[8];
#pragma unroll
        for (int j = 0; j < 8; ++j) {
            const size_t base = ((size_t)b * NCT + (g * 8 + j)) * DI + c;
            he[j] = hend[base * 16 + s];
            sd[j] = sumdt[base];
        }
#pragma unroll
        for (int j = 0; j < 8; ++j) {
            const size_t base = ((size_t)b * NCT + (g * 8 + j)) * DI + c;
            hend[base * 16 + s] = hs;
            hs = __expf(Aval * sd[j]) * hs + he[j];
        }
    }
}

// ---------------------------------------------------------------------------
// tscan3 with LDS B+C slab (4 KB); epilogue fuses the gated 3-way bf16 split.
// ---------------------------------------------------------------------------
__global__ __launch_bounds__(256) void tscan3(const float* __restrict__ dtb,
                                              const float* __restrict__ u,
                                              const float* __restrict__ Pp,
                                              const float* __restrict__ zs,
                                              const float* __restrict__ A_log,
                                              const float* __restrict__ hstart,
                                              unsigned short* __restrict__ G1,
                                              unsigned short* __restrict__ G2,
                                              unsigned short* __restrict__ G3) {
    __shared__ float BCsl[CTL][32];
    const int c = blockIdx.x * 256 + threadIdx.x;
    const int ch = blockIdx.y;
    const int b = blockIdx.z;
    const size_t m0 = (size_t)b * LL + (size_t)ch * CTL;

    {
        const int row = threadIdx.x >> 3;           // 0..31
        const int c4 = (threadIdx.x & 7) * 4;       // 0..28
        float4 s = make_float4(0.f, 0.f, 0.f, 0.f);
#pragma unroll
        for (int kz = 0; kz < 4; ++kz) {
            const float4 v = *(const float4*)&Pp[(size_t)kz * MROWS * 96
                                                 + (m0 + row) * 96 + 64 + c4];
            s.x += v.x; s.y += v.y; s.z += v.z; s.w += v.w;
        }
        *(float4*)&BCsl[row][c4] = s;
    }

    float A[16];
#pragma unroll
    for (int s4 = 0; s4 < 16; s4 += 4) {
        float4 v = *(const float4*)&A_log[c * 16 + s4];
        A[s4] = -__expf(v.x); A[s4 + 1] = -__expf(v.y);
        A[s4 + 2] = -__expf(v.z); A[s4 + 3] = -__expf(v.w);
    }
    float h[16];
    const size_t o = (((size_t)b * NCT + ch) * DI + c) * 16;
#pragma unroll
    for (int s4 = 0; s4 < 16; s4 += 4) {
        float4 v = *(const float4*)&hstart[o + s4];
        h[s4] = v.x; h[s4 + 1] = v.y; h[s4 + 2] = v.z; h[s4 + 3] = v.w;
    }
    __syncthreads();

#pragma unroll 2
    for (int t = 0; t < CTL; ++t) {
        const size_t m = m0 + t;
        const float dt = dtb[m * DI + c];
        const float uv = u[m * DI + c];
        const float dtu = dt * uv;
        float bcv[32];
#pragma unroll
        for (int s4 = 0; s4 < 32; s4 += 4) {
            const float4 v = *(const float4*)&BCsl[t][s4];
            bcv[s4] = v.x; bcv[s4 + 1] = v.y; bcv[s4 + 2] = v.z; bcv[s4 + 3] = v.w;
        }
        float y = 0.f;
#pragma unroll
        for (int s = 0; s < 16; ++s) {
            const float ab = __expf(dt * A[s]);
            h[s] = ab * h[s] + bcv[s] * dtu;
            y += bcv[16 + s] * h[s];
        }
        const float g = y * zs[m * DI + c];
        unsigned short g1, g2, g3;
        split1(g, g1, g2, g3);
        G1[m * DI + c] = g1;
        G2[m * DI + c] = g2;
        G3[m * DI + c] = g3;
    }
}

// ---------------------------------------------------------------------------
// Workspace (floats), max extent 21,168,128 (proven footprint):
//   phase A: xz [0,8388608); A splits @8388608/9437184/10485760;
//            B splits @11534336/13631488/15728640
//   phase B: Pp [0,786432)  (live through tscan3);
//            u [8388608,12582912), zs [12582912,16777216),
//            dtb [16973824,21168128)
//   phase C (scan): hend = d_out (2,097,152 fl, dead until GEMM2);
//            sumdt [7077888,7143424);
//            G1s [786432,2883584), G2s [2883584,4980736), G3s [4980736,7077888)
//   phase D: Wo splits @8388608/9437184/10485760 (1,048,576-fl stride —
//            FIXED round-15 overlap bug; u dead after tscan3);
//            GEMM2 partials z=1..3 @11534336 (3 x 2097152, zs/dtb dead)
// ---------------------------------------------------------------------------
extern "C" void kernel_launch(void* const* d_in, const int* in_sizes, int n_in,
                              void* d_out, int out_size, void* d_ws, size_t ws_size,
                              hipStream_t stream) {
    const float* inputs = (const float*)d_in[0];
    const float* W_in   = (const float*)d_in[1];
    const float* W_conv = (const float*)d_in[2];
    const float* b_conv = (const float*)d_in[3];
    const float* W_x    = (const float*)d_in[4];
    const float* W_dt   = (const float*)d_in[5];
    const float* b_dt   = (const float*)d_in[6];
    const float* A_log  = (const float*)d_in[7];
    const float* W_out  = (const float*)d_in[8];
    float* out = (float*)d_out;

    float* ws = (float*)d_ws;
    float* xz      = ws;
    float* Pp      = ws;                      // proj partials (4 x 196608)
    unsigned short* G1s  = (unsigned short*)(ws + 786432);
    unsigned short* G2s  = (unsigned short*)(ws + 2883584);
    unsigned short* G3s  = (unsigned short*)(ws + 4980736);
    float* sumdt   = ws + 7077888;            // 65536
    float* hend    = out;                     // 2,097,152 fl — dead until GEMM2
    unsigned short* A1s = (unsigned short*)(ws + 8388608);
    unsigned short* A2s = (unsigned short*)(ws + 9437184);
    unsigned short* A3s = (unsigned short*)(ws + 10485760);
    unsigned short* B1s = (unsigned short*)(ws + 11534336);
    unsigned short* B2s = (unsigned short*)(ws + 13631488);
    unsigned short* B3s = (unsigned short*)(ws + 15728640);
    float* u       = ws + 8388608;
    float* zs      = ws + 12582912;
    float* dtb     = ws + 16973824;
    unsigned short* Wo1s = (unsigned short*)(ws + 8388608);   // after tscan3
    unsigned short* Wo2s = (unsigned short*)(ws + 9437184);   // +1,048,576 fl
    unsigned short* Wo3s = (unsigned short*)(ws + 10485760);  // +1,048,576 fl
    float* P2p     = ws + 11534336;           // GEMM2 partials z=1..3

    // 0) split inputs + W_in into bf16 triples (one launch)
    split3_2<<<3072, 256, 0, stream>>>(
        (const float4*)inputs, (ushort4*)A1s, (ushort4*)A2s, (ushort4*)A3s, 524288,
        (const float4*)W_in, (ushort4*)B1s, (ushort4*)B2s, (ushort4*)B3s, 1048576, 1024);
    // 1) xz = inputs @ W_in^T via split-bf16 MFMA
    gemm_mfma_split<<<dim3(32, 16, 1), 256, 0, stream>>>(
        A1s, A2s, A3s, B1s, B2s, B3s, xz, xz, MROWS, 2 * DI, DD, DD);
    // 2) u, zs row-major, 8 t-steps/thread (overwrites dead A/B splits)
    conv_silu_rm8<<<dim3(DI / 256, LL / 8, BB), 256, 0, stream>>>(xz, W_conv, b_conv, u, zs);
    // 3) proj split-K=4 -> Pp partials (no reduce kernel; consumers sum)
    proj_gemm_sk<<<dim3(MROWS / 16, 4), 256, 0, stream>>>(u, W_x, Pp);
    // 4) dtb[m][DI] from partials
    dt_gemm<<<dim3(DI / 256, MROWS / 16), 256, 0, stream>>>(Pp, W_dt, b_dt, dtb);
    // 5) transposed chunked scan; tscan3 writes G splits directly
    tscan1<<<dim3(DI / 256, NCT, BB), 256, 0, stream>>>(dtb, u, Pp, A_log, hend, sumdt);
    tscan2<<<dim3(BB * DI * SS / 256), 256, 0, stream>>>(hend, sumdt, A_log);
    tscan3<<<dim3(DI / 256, NCT, BB), 256, 0, stream>>>(dtb, u, Pp, zs, A_log, hend,
                                                        G1s, G2s, G3s);
    // 6) split W_out (into dead u region)
    split3<<<2048, 256, 0, stream>>>((const float4*)W_out, (ushort4*)Wo1s,
                                     (ushort4*)Wo2s, (ushort4*)Wo3s, 524288);
    // 7) out = gated @ W_out^T, split-K=4: z=0 -> out, z=1..3 -> P2p
    gemm_mfma_split<<<dim3(8, 16, 4), 256, 0, stream>>>(
        G1s, G2s, G3s, Wo1s, Wo2s, Wo3s, out, P2p, MROWS, DD, DI, DI / 4);
    // 7b) out += sum of 3 partials
    reduce_add3<<<2048, 256, 0, stream>>>((float4*)out, (const float4*)P2p, 524288);
}

// Round 17
// 373.955 us; speedup vs baseline: 1.0397x; 1.0397x over previous
//
#include <hip/hip_runtime.h>
#include <hip/hip_bf16.h>

// Problem constants
#define BB 2
#define LL 1024
#define DD 1024
#define DI 2048
#define SS 16
#define KK 4
#define RR 64
#define MROWS (BB*LL)   // 2048
#define NCT 32          // t-chunks for scan
#define CTL 32          // steps per chunk (LL / NCT)

typedef __attribute__((ext_vector_type(8))) short short8;     // 8 bf16 = 4 VGPR
typedef __attribute__((ext_vector_type(4))) float floatx4;    // MFMA C/D

// RNE fp32 -> bf16 bits
__device__ __forceinline__ unsigned short f2bf(float v) {
    unsigned int u = __float_as_uint(v);
    return (unsigned short)((u + 0x7FFFu + ((u >> 16) & 1u)) >> 16);
}
__device__ __forceinline__ float bf2f(unsigned short h) {
    return __uint_as_float(((unsigned int)h) << 16);
}
__device__ __forceinline__ void split1(float v, unsigned short& a,
                                       unsigned short& b, unsigned short& c) {
    a = f2bf(v);
    float r = v - bf2f(a);
    b = f2bf(r);
    float r2 = r - bf2f(b);
    c = f2bf(r2);
}

__device__ __forceinline__ void split3_body(const float4* __restrict__ src,
                                            ushort4* __restrict__ d1,
                                            ushort4* __restrict__ d2,
                                            ushort4* __restrict__ d3,
                                            int i0, int stride, int n4) {
    for (int i = i0; i < n4; i += stride) {
        const float4 v = src[i];
        ushort4 o1, o2, o3;
        split1(v.x, o1.x, o2.x, o3.x);
        split1(v.y, o1.y, o2.y, o3.y);
        split1(v.z, o1.z, o2.z, o3.z);
        split1(v.w, o1.w, o2.w, o3.w);
        d1[i] = o1; d2[i] = o2; d3[i] = o3;
    }
}

__global__ __launch_bounds__(256) void split3(const float4* __restrict__ src,
                                              ushort4* __restrict__ d1,
                                              ushort4* __restrict__ d2,
                                              ushort4* __restrict__ d3, int n4) {
    split3_body(src, d1, d2, d3, blockIdx.x * 256 + threadIdx.x, gridDim.x * 256, n4);
}

__global__ __launch_bounds__(256) void split3_2(
    const float4* __restrict__ s0, ushort4* __restrict__ a1,
    ushort4* __restrict__ a2, ushort4* __restrict__ a3, int n0,
    const float4* __restrict__ s1, ushort4* __restrict__ b1,
    ushort4* __restrict__ b2, ushort4* __restrict__ b3, int n1, int nb0) {
    if ((int)blockIdx.x < nb0) {
        split3_body(s0, a1, a2, a3, blockIdx.x * 256 + threadIdx.x, nb0 * 256, n0);
    } else {
        const int nb1 = gridDim.x - nb0;
        split3_body(s1, b1, b2, b3, (blockIdx.x - nb0) * 256 + threadIdx.x, nb1 * 256, n1);
    }
}

// ---------------------------------------------------------------------------
// Split-bf16 MFMA GEMM (k-quad-major LDS, reg prefetch).
// ---------------------------------------------------------------------------
__global__ __launch_bounds__(256, 3) void gemm_mfma_split(
    const unsigned short* __restrict__ A1, const unsigned short* __restrict__ A2,
    const unsigned short* __restrict__ A3,
    const unsigned short* __restrict__ B1, const unsigned short* __restrict__ B2,
    const unsigned short* __restrict__ B3,
    float* __restrict__ C0, float* __restrict__ Cpart,
    int M, int N, int Kstride, int Klen) {
    __shared__ unsigned short As[3][4][128][8];
    __shared__ unsigned short Bs[3][4][128][8];
    const int tid = threadIdx.x;
    const int bm = blockIdx.y * 128;
    const int bn = blockIdx.x * 128;
    const int Koff = blockIdx.z * Klen;
    float* __restrict__ C = (blockIdx.z == 0)
        ? C0 : (Cpart + (size_t)(blockIdx.z - 1) * M * N);

    const int lane = tid & 63;
    const int wv = tid >> 6;
    const int lm = lane & 15;
    const int kq = lane >> 4;
    const int wm = (wv >> 1) * 64;
    const int wn = (wv & 1) * 64;

    floatx4 acc[4][4];
    const floatx4 zf = {0.f, 0.f, 0.f, 0.f};
#pragma unroll
    for (int i = 0; i < 4; ++i)
#pragma unroll
        for (int j = 0; j < 4; ++j) acc[i][j] = zf;

    const int r0 = tid >> 1;
    const int cc = tid & 1;
    const int cc0 = cc * 16;
    const int cc1 = cc0 + 8;
    const int q0 = cc * 2, q1 = cc * 2 + 1;

    const unsigned short* __restrict__ Ar1 = A1 + (size_t)(bm + r0) * Kstride;
    const unsigned short* __restrict__ Ar2 = A2 + (size_t)(bm + r0) * Kstride;
    const unsigned short* __restrict__ Ar3 = A3 + (size_t)(bm + r0) * Kstride;
    const unsigned short* __restrict__ Br1 = B1 + (size_t)(bn + r0) * Kstride;
    const unsigned short* __restrict__ Br2 = B2 + (size_t)(bn + r0) * Kstride;
    const unsigned short* __restrict__ Br3 = B3 + (size_t)(bn + r0) * Kstride;

    short8 pA[3][2], pB[3][2];
#define LOADK(kt)                                                     \
    {                                                                 \
        pA[0][0] = *(const short8*)&Ar1[(kt) + cc0];                  \
        pA[0][1] = *(const short8*)&Ar1[(kt) + cc1];                  \
        pA[1][0] = *(const short8*)&Ar2[(kt) + cc0];                  \
        pA[1][1] = *(const short8*)&Ar2[(kt) + cc1];                  \
        pA[2][0] = *(const short8*)&Ar3[(kt) + cc0];                  \
        pA[2][1] = *(const short8*)&Ar3[(kt) + cc1];                  \
        pB[0][0] = *(const short8*)&Br1[(kt) + cc0];                  \
        pB[0][1] = *(const short8*)&Br1[(kt) + cc1];                  \
        pB[1][0] = *(const short8*)&Br2[(kt) + cc0];                  \
        pB[1][1] = *(const short8*)&Br2[(kt) + cc1];                  \
        pB[2][0] = *(const short8*)&Br3[(kt) + cc0];                  \
        pB[2][1] = *(const short8*)&Br3[(kt) + cc1];                  \
    }

#define PROD(p, bfq)                                                                     \
        _Pragma("unroll")                                                                \
        for (int i = 0; i < 4; ++i)                                                      \
            _Pragma("unroll")                                                            \
            for (int j = 0; j < 4; ++j)                                                  \
                acc[i][j] = __builtin_amdgcn_mfma_f32_16x16x32_bf16(af[p][i], bfq[j],    \
                                                                    acc[i][j], 0, 0, 0);

    LOADK(Koff)
    for (int kt = Koff; kt < Koff + Klen; kt += 32) {
#pragma unroll
        for (int p = 0; p < 3; ++p) {
            *(short8*)&As[p][q0][r0][0] = pA[p][0];
            *(short8*)&As[p][q1][r0][0] = pA[p][1];
            *(short8*)&Bs[p][q0][r0][0] = pB[p][0];
            *(short8*)&Bs[p][q1][r0][0] = pB[p][1];
        }
        __syncthreads();

        const int ktn = (kt + 32 < Koff + Klen) ? (kt + 32) : Koff;
        LOADK(ktn)

        short8 af[3][4];
#pragma unroll
        for (int p = 0; p < 3; ++p)
#pragma unroll
            for (int i = 0; i < 4; ++i)
                af[p][i] = *(const short8*)&As[p][kq][wm + i * 16 + lm][0];

        {
            short8 bfq[4];
#pragma unroll
            for (int j = 0; j < 4; ++j) bfq[j] = *(const short8*)&Bs[0][kq][wn + j * 16 + lm][0];
            PROD(0, bfq)
            PROD(1, bfq)
            PROD(2, bfq)
        }
        {
            short8 bfq[4];
#pragma unroll
            for (int j = 0; j < 4; ++j) bfq[j] = *(const short8*)&Bs[1][kq][wn + j * 16 + lm][0];
            PROD(0, bfq)
            PROD(1, bfq)
        }
        {
            short8 bfq[4];
#pragma unroll
            for (int j = 0; j < 4; ++j) bfq[j] = *(const short8*)&Bs[2][kq][wn + j * 16 + lm][0];
            PROD(0, bfq)
        }
        __syncthreads();
    }
#undef PROD
#undef LOADK

#pragma unroll
    for (int i = 0; i < 4; ++i) {
        const int mrow = bm + wm + i * 16 + kq * 4;
#pragma unroll
        for (int j = 0; j < 4; ++j) {
            const int col = bn + wn + j * 16 + lm;
#pragma unroll
            for (int r = 0; r < 4; ++r)
                C[(size_t)(mrow + r) * N + col] = acc[i][j][r];
        }
    }
}

// ---------------------------------------------------------------------------
__global__ __launch_bounds__(256) void reduce_add3(float4* __restrict__ dst,
                                                   const float4* __restrict__ src,
                                                   int n4) {
    for (int i = blockIdx.x * 256 + threadIdx.x; i < n4; i += gridDim.x * 256) {
        float4 a = dst[i];
        const float4 p0 = src[i];
        const float4 p1 = src[i + (size_t)n4];
        const float4 p2 = src[i + (size_t)2 * n4];
        a.x += p0.x + p1.x + p2.x;
        a.y += p0.y + p1.y + p2.y;
        a.z += p0.z + p1.z + p2.z;
        a.w += p0.w + p1.w + p2.w;
        dst[i] = a;
    }
}

// ---------------------------------------------------------------------------
// Depthwise causal conv (K=4) + bias + silu, 8 t-steps/thread
// ---------------------------------------------------------------------------
__global__ __launch_bounds__(256) void conv_silu_rm8(const float* __restrict__ xz,
                                                     const float* __restrict__ Wc,
                                                     const float* __restrict__ bc,
                                                     float* __restrict__ u,
                                                     float* __restrict__ zs) {
    const int c = blockIdx.x * 256 + threadIdx.x;
    const int t0 = blockIdx.y * 8;
    const int b = blockIdx.z;
    const float* xcol = xz + (size_t)b * LL * (2 * DI) + c;
    const float w0 = Wc[c * 4 + 0], w1 = Wc[c * 4 + 1];
    const float w2 = Wc[c * 4 + 2], w3 = Wc[c * 4 + 3];
    const float bcv = bc[c];

    float x[11];
#pragma unroll
    for (int i = 0; i < 11; ++i) {
        const int t = t0 - 3 + i;
        x[i] = (t >= 0) ? xcol[(size_t)t * (2 * DI)] : 0.f;
    }
#pragma unroll
    for (int j = 0; j < 8; ++j) {
        const float acc = bcv + x[j] * w0 + x[j + 1] * w1 + x[j + 2] * w2 + x[j + 3] * w3;
        const float zv = xcol[(size_t)(t0 + j) * (2 * DI) + DI];
        const size_t o = ((size_t)b * LL + t0 + j) * DI + c;
        u[o]  = acc / (1.f + __expf(-acc));
        zs[o] = zv / (1.f + __expf(-zv));
    }
}

// ---------------------------------------------------------------------------
// proj split-K=4 with float4 LDS inner loop
// ---------------------------------------------------------------------------
__global__ __launch_bounds__(256) void proj_gemm_sk(const float* __restrict__ U,
                                                    const float* __restrict__ Wx,
                                                    float* __restrict__ Pp) {
    const int BKp = 64;
    __shared__ float Us[16][68];
    __shared__ float Ws[96][68];
    const int tid = threadIdx.x;
    const int m0 = blockIdx.x * 16;
    const int Koff = blockIdx.y * (DI / 4);
    float* __restrict__ P = Pp + (size_t)blockIdx.y * MROWS * 96;
    const int tx = tid & 31;
    const int ty = tid >> 5;
    float acc[2][3] = {{0.f, 0.f, 0.f}, {0.f, 0.f, 0.f}};

    for (int kt = Koff; kt < Koff + DI / 4; kt += BKp) {
        {
            const int r = tid >> 4;
            const int c4 = (tid & 15) << 2;
            *(float4*)&Us[r][c4] = *(const float4*)&U[(size_t)(m0 + r) * DI + kt + c4];
        }
#pragma unroll
        for (int i = 0; i < 6; ++i) {
            const int idx = tid + i * 256;
            const int r = idx >> 4;
            const int c4 = (idx & 15) << 2;
            *(float4*)&Ws[r][c4] = *(const float4*)&Wx[(size_t)r * DI + kt + c4];
        }
        __syncthreads();
#pragma unroll
        for (int k4 = 0; k4 < BKp; k4 += 4) {
            const float4 u0 = *(const float4*)&Us[ty * 2][k4];
            const float4 u1 = *(const float4*)&Us[ty * 2 + 1][k4];
#pragma unroll
            for (int j = 0; j < 3; ++j) {
                const float4 w = *(const float4*)&Ws[tx + 32 * j][k4];
                acc[0][j] += u0.x * w.x + u0.y * w.y + u0.z * w.z + u0.w * w.w;
                acc[1][j] += u1.x * w.x + u1.y * w.y + u1.z * w.z + u1.w * w.w;
            }
        }
        __syncthreads();
    }
#pragma unroll
    for (int i = 0; i < 2; ++i)
#pragma unroll
        for (int j = 0; j < 3; ++j)
            P[(size_t)(m0 + ty * 2 + i) * 96 + tx + 32 * j] = acc[i][j];
}

// ---------------------------------------------------------------------------
// proj reduce: P[i] = sum_{kz<4} Pp[kz][i]
// ---------------------------------------------------------------------------
__global__ __launch_bounds__(256) void proj_reduce(float4* __restrict__ P,
                                                   const float4* __restrict__ Pp,
                                                   int n4) {
    for (int i = blockIdx.x * 256 + threadIdx.x; i < n4; i += gridDim.x * 256) {
        const float4 a = Pp[i];
        const float4 b = Pp[i + (size_t)n4];
        const float4 c = Pp[i + (size_t)2 * n4];
        const float4 d = Pp[i + (size_t)3 * n4];
        P[i] = make_float4(a.x + b.x + c.x + d.x, a.y + b.y + c.y + d.y,
                           a.z + b.z + c.z + d.z, a.w + b.w + c.w + d.w);
    }
}

// ---------------------------------------------------------------------------
// dt[m][c] = softplus(P[m][:64] @ W_dt^T + b_dt)
// ---------------------------------------------------------------------------
__global__ __launch_bounds__(256) void dt_gemm(const float* __restrict__ P,
                                               const float* __restrict__ Wdt,
                                               const float* __restrict__ bdt,
                                               float* __restrict__ dtb) {
    __shared__ float ps[16][68];
    const int tid = threadIdx.x;
    const int c = blockIdx.x * 256 + tid;
    const int m0 = blockIdx.y * 16;
    {
        const int r = tid >> 4;
        const int c4 = (tid & 15) << 2;
        *(float4*)&ps[r][c4] = *(const float4*)&P[(size_t)(m0 + r) * 96 + c4];
    }
    float w[64];
#pragma unroll
    for (int r4 = 0; r4 < 64; r4 += 4) {
        float4 v = *(const float4*)&Wdt[(size_t)c * 64 + r4];
        w[r4] = v.x; w[r4 + 1] = v.y; w[r4 + 2] = v.z; w[r4 + 3] = v.w;
    }
    const float bd = bdt[c];
    __syncthreads();
#pragma unroll 4
    for (int m = 0; m < 16; ++m) {
        float acc = bd;
#pragma unroll
        for (int r4 = 0; r4 < 64; r4 += 4) {
            float4 p = *(const float4*)&ps[m][r4];
            acc += p.x * w[r4] + p.y * w[r4 + 1] + p.z * w[r4 + 2] + p.w * w[r4 + 3];
        }
        const float sp = (acc > 20.f) ? acc : __logf(1.f + __expf(acc));
        dtb[(size_t)(m0 + m) * DI + c] = sp;
    }
}

// ---------------------------------------------------------------------------
// Transposed chunked scan passes 1-2
// ---------------------------------------------------------------------------
__global__ __launch_bounds__(256) void tscan1(const float* __restrict__ dtb,
                                              const float* __restrict__ u,
                                              const float* __restrict__ P,
                                              const float* __restrict__ A_log,
                                              float* __restrict__ hend,
                                              float* __restrict__ sumdt) {
    const int c = blockIdx.x * 256 + threadIdx.x;
    const int ch = blockIdx.y;
    const int b = blockIdx.z;

    float A[16];
#pragma unroll
    for (int s4 = 0; s4 < 16; s4 += 4) {
        float4 v = *(const float4*)&A_log[c * 16 + s4];
        A[s4] = -__expf(v.x); A[s4 + 1] = -__expf(v.y);
        A[s4 + 2] = -__expf(v.z); A[s4 + 3] = -__expf(v.w);
    }
    float h[16];
#pragma unroll
    for (int s = 0; s < 16; ++s) h[s] = 0.f;
    float sd = 0.f;

    const size_t m0 = (size_t)b * LL + (size_t)ch * CTL;
#pragma unroll 2
    for (int t = 0; t < CTL; ++t) {
        const size_t m = m0 + t;
        const float dt = dtb[m * DI + c];
        const float uv = u[m * DI + c];
        const float dtu = dt * uv;
        sd += dt;
        const float* __restrict__ bc = P + m * 96 + 64;
#pragma unroll
        for (int s = 0; s < 16; ++s) {
            const float ab = __expf(dt * A[s]);
            h[s] = ab * h[s] + bc[s] * dtu;
        }
    }
    const size_t o = (((size_t)b * NCT + ch) * DI + c) * 16;
#pragma unroll
    for (int s4 = 0; s4 < 16; s4 += 4)
        *(float4*)&hend[o + s4] = make_float4(h[s4], h[s4 + 1], h[s4 + 2], h[s4 + 3]);
    sumdt[((size_t)b * NCT + ch) * DI + c] = sd;
}

// ---------------------------------------------------------------------------
__global__ __launch_bounds__(256) void tscan2(float* __restrict__ hend,
                                              const float* __restrict__ sumdt,
                                              const float* __restrict__ A_log) {
    const int id = blockIdx.x * 256 + threadIdx.x;
    const int s = id & 15;
    const int c = (id >> 4) & (DI - 1);
    const int b = id >> 15;
    const float Aval = -__expf(A_log[c * 16 + s]);
    float hs = 0.f;
#pragma unroll
    for (int g = 0; g < 4; ++g) {
        float he[8], sd[8];
#pragma unroll
        for (int j = 0; j < 8; ++j) {
            const size_t base = ((size_t)b * NCT + (g * 8 + j)) * DI + c;
            he[j] = hend[base * 16 + s];
            sd[j] = sumdt[base];
        }
#pragma unroll
        for (int j = 0; j < 8; ++j) {
            const size_t base = ((size_t)b * NCT + (g * 8 + j)) * DI + c;
            hend[base * 16 + s] = hs;
            hs = __expf(Aval * sd[j]) * hs + he[j];
        }
    }
}

// ---------------------------------------------------------------------------
// Pass 3: re-run from h_start; epilogue fuses the gated 3-way bf16 split.
// ---------------------------------------------------------------------------
__global__ __launch_bounds__(256) void tscan3(const float* __restrict__ dtb,
                                              const float* __restrict__ u,
                                              const float* __restrict__ P,
                                              const float* __restrict__ zs,
                                              const float* __restrict__ A_log,
                                              const float* __restrict__ hstart,
                                              unsigned short* __restrict__ G1,
                                              unsigned short* __restrict__ G2,
                                              unsigned short* __restrict__ G3) {
    const int c = blockIdx.x * 256 + threadIdx.x;
    const int ch = blockIdx.y;
    const int b = blockIdx.z;

    float A[16];
#pragma unroll
    for (int s4 = 0; s4 < 16; s4 += 4) {
        float4 v = *(const float4*)&A_log[c * 16 + s4];
        A[s4] = -__expf(v.x); A[s4 + 1] = -__expf(v.y);
        A[s4 + 2] = -__expf(v.z); A[s4 + 3] = -__expf(v.w);
    }
    float h[16];
    const size_t o = (((size_t)b * NCT + ch) * DI + c) * 16;
#pragma unroll
    for (int s4 = 0; s4 < 16; s4 += 4) {
        float4 v = *(const float4*)&hstart[o + s4];
        h[s4] = v.x; h[s4 + 1] = v.y; h[s4 + 2] = v.z; h[s4 + 3] = v.w;
    }

    const size_t m0 = (size_t)b * LL + (size_t)ch * CTL;
#pragma unroll 2
    for (int t = 0; t < CTL; ++t) {
        const size_t m = m0 + t;
        const float dt = dtb[m * DI + c];
        const float uv = u[m * DI + c];
        const float dtu = dt * uv;
        const float* __restrict__ bc = P + m * 96 + 64;
        float y = 0.f;
#pragma unroll
        for (int s = 0; s < 16; ++s) {
            const float ab = __expf(dt * A[s]);
            h[s] = ab * h[s] + bc[s] * dtu;
            y += bc[16 + s] * h[s];
        }
        const float g = y * zs[m * DI + c];
        unsigned short g1, g2, g3;
        split1(g, g1, g2, g3);
        G1[m * DI + c] = g1;
        G2[m * DI + c] = g2;
        G3[m * DI + c] = g3;
    }
}

// ---------------------------------------------------------------------------
// Workspace (floats), max extent 21,168,128 (proven footprint):
//   phase A: xz [0,8388608); A splits @8388608/9437184/10485760;
//            B splits @11534336/13631488/15728640
//   phase B: Pp [0,786432); u [8388608,12582912), zs [12582912,16777216),
//            P [16777216,16973824), dtb [16973824,21168128)
//   phase C (scan): hend = d_out (2,097,152 fl, dead until GEMM2);
//            sumdt [6291456,6356992);
//            G1s [0,2097152), G2s [2097152,4194304), G3s [4194304,6291456)
//   phase D: Wo splits @8388608/9437184/10485760 (u dead);
//            GEMM2 partials z=1..3 @11534336 (3 x 2097152)
// ---------------------------------------------------------------------------
extern "C" void kernel_launch(void* const* d_in, const int* in_sizes, int n_in,
                              void* d_out, int out_size, void* d_ws, size_t ws_size,
                              hipStream_t stream) {
    const float* inputs = (const float*)d_in[0];
    const float* W_in   = (const float*)d_in[1];
    const float* W_conv = (const float*)d_in[2];
    const float* b_conv = (const float*)d_in[3];
    const float* W_x    = (const float*)d_in[4];
    const float* W_dt   = (const float*)d_in[5];
    const float* b_dt   = (const float*)d_in[6];
    const float* A_log  = (const float*)d_in[7];
    const float* W_out  = (const float*)d_in[8];
    float* out = (float*)d_out;

    float* ws = (float*)d_ws;
    float* xz      = ws;
    float* Pp      = ws;                      // proj partials (4 x 196608)
    unsigned short* G1s  = (unsigned short*)(ws);             // 4.2M ushorts
    unsigned short* G2s  = (unsigned short*)(ws + 2097152);
    unsigned short* G3s  = (unsigned short*)(ws + 4194304);
    float* sumdt   = ws + 6291456;            // 65536
    float* hend    = out;                     // 2,097,152 fl — dead until GEMM2
    unsigned short* A1s = (unsigned short*)(ws + 8388608);
    unsigned short* A2s = (unsigned short*)(ws + 9437184);
    unsigned short* A3s = (unsigned short*)(ws + 10485760);
    unsigned short* B1s = (unsigned short*)(ws + 11534336);
    unsigned short* B2s = (unsigned short*)(ws + 13631488);
    unsigned short* B3s = (unsigned short*)(ws + 15728640);
    float* u       = ws + 8388608;
    float* zs      = ws + 12582912;
    float* P       = ws + 16777216;
    float* dtb     = ws + 16973824;
    unsigned short* Wo1s = (unsigned short*)(ws + 8388608);   // after tscan3
    unsigned short* Wo2s = (unsigned short*)(ws + 9437184);
    unsigned short* Wo3s = (unsigned short*)(ws + 10485760);
    float* P2p     = ws + 11534336;           // GEMM2 partials z=1..3

    // 0) split inputs + W_in into bf16 triples (one launch)
    split3_2<<<3072, 256, 0, stream>>>(
        (const float4*)inputs, (ushort4*)A1s, (ushort4*)A2s, (ushort4*)A3s, 524288,
        (const float4*)W_in, (ushort4*)B1s, (ushort4*)B2s, (ushort4*)B3s, 1048576, 1024);
    // 1) xz = inputs @ W_in^T via split-bf16 MFMA (512 blocks)
    gemm_mfma_split<<<dim3(32, 16, 1), 256, 0, stream>>>(
        A1s, A2s, A3s, B1s, B2s, B3s, xz, xz, MROWS, 2 * DI, DD, DD);
    // 2) u, zs row-major, 8 t-steps/thread (overwrites dead A/B splits)
    conv_silu_rm8<<<dim3(DI / 256, LL / 8, BB), 256, 0, stream>>>(xz, W_conv, b_conv, u, zs);
    // 3) proj split-K=4 -> partials -> P[m][96]
    proj_gemm_sk<<<dim3(MROWS / 16, 4), 256, 0, stream>>>(u, W_x, Pp);
    proj_reduce<<<192, 256, 0, stream>>>((float4*)P, (const float4*)Pp, 49152);
    // 4) dtb[m][DI]
    dt_gemm<<<dim3(DI / 256, MROWS / 16), 256, 0, stream>>>(P, W_dt, b_dt, dtb);
    // 5) transposed chunked scan; tscan3 writes G splits directly
    tscan1<<<dim3(DI / 256, NCT, BB), 256, 0, stream>>>(dtb, u, P, A_log, hend, sumdt);
    tscan2<<<dim3(BB * DI * SS / 256), 256, 0, stream>>>(hend, sumdt, A_log);
    tscan3<<<dim3(DI / 256, NCT, BB), 256, 0, stream>>>(dtb, u, P, zs, A_log, hend,
                                                        G1s, G2s, G3s);
    // 6) split W_out (into dead u region)
    split3<<<2048, 256, 0, stream>>>((const float4*)W_out, (ushort4*)Wo1s,
                                     (ushort4*)Wo2s, (ushort4*)Wo3s, 524288);
    // 7) out = gated @ W_out^T, split-K=4: z=0 -> out, z=1..3 -> P2p
    gemm_mfma_split<<<dim3(8, 16, 4), 256, 0, stream>>>(
        G1s, G2s, G3s, Wo1s, Wo2s, Wo3s, out, P2p, MROWS, DD, DI, DI / 4);
    // 7b) out += sum of 3 partials
    reduce_add3<<<2048, 256, 0, stream>>>((float4*)out, (const float4*)P2p, 524288);
}